// Round 3
// baseline (408.452 us; speedup 1.0000x reference)
//
#include <hip/hip_runtime.h>
#include <hip/hip_bf16.h>

typedef __attribute__((ext_vector_type(8))) short short8;
typedef __attribute__((ext_vector_type(4))) float float4v;
typedef __attribute__((ext_vector_type(2))) unsigned int uint2v;
typedef __attribute__((ext_vector_type(4))) unsigned int uint4v;

#define NSAMP 10000
#define CIN   64
#define TLEN  64
#define COUT  64     // channels after GLU
#define TOUT  62

// fp32 -> bf16 bits, round-to-nearest-even (inputs are never NaN/Inf)
static __device__ __forceinline__ ushort f2bf(float v) {
    unsigned int x = __float_as_uint(v);
    return (ushort)((x + 0x7fffu + ((x >> 16) & 1u)) >> 16);
}

// packed fp32x2 -> bf16x2 (lo = a, hi = b), RNE
static __device__ __forceinline__ unsigned int cvt_pk_bf16(float a, float b) {
    unsigned int r;
    asm("v_cvt_pk_bf16_f32 %0, %1, %2" : "=v"(r) : "v"(a), "v"(b));
    return r;
}

// Pre-permute + downconvert weights: Wa[co][kk], kk = k*64 + ci (bf16 bits).
// src: float w[co][ci][k] (strides 192, 3, 1)
__global__ void prep_weights(const float* __restrict__ w, ushort* __restrict__ wa) {
    int o = blockIdx.x * blockDim.x + threadIdx.x;
    if (o >= 128 * 192) return;
    int co = o / 192;
    int kk = o - co * 192;
    int k  = kk >> 6;
    int ci = kk & 63;
    wa[o] = f2bf(w[co * 192 + ci * 3 + k]);
}

// prep_x: one sample per block. x[n][ci][t] fp32 -> xt[n][t][ci] bf16.
// Transpose via swizzled LDS (R1-proven staging), coalesced in and out.
__global__ __launch_bounds__(256, 8)
void prep_x(const float* __restrict__ x, ushort* __restrict__ xt) {
    __shared__ __align__(16) ushort b[64 * 64];   // 8 KB
    const int n   = blockIdx.x;
    const int tid = threadIdx.x;

    const int cig = tid >> 4;         // ci group of 4
    const int ts  = (tid & 15) * 4;   // t base
    const float* p = x + (long)n * (CIN * TLEN) + cig * 4 * TLEN + ts;
    float4v v0 = *(const float4v*)(p);
    float4v v1 = *(const float4v*)(p + TLEN);
    float4v v2 = *(const float4v*)(p + 2 * TLEN);
    float4v v3 = *(const float4v*)(p + 3 * TLEN);
    char* base = (char*)b;
#pragma unroll
    for (int r = 0; r < 4; ++r) {
        int t = ts + r;
        uint2v val;
        val.x = cvt_pk_bf16(v0[r], v1[r]);   // ci 4cig, 4cig+1
        val.y = cvt_pk_bf16(v2[r], v3[r]);   // ci 4cig+2, 4cig+3
        *(uint2v*)(base + t * 128 + ((cig * 8) ^ ((t & 7) << 4))) = val;
    }
    __syncthreads();

    // writeback: 512 chunks of 16B, 2 per thread, coalesced
    char* outn = (char*)(xt + (long)n * (TLEN * CIN));
#pragma unroll
    for (int i = 0; i < 2; ++i) {
        int f = i * 256 + tid;
        int t = f >> 3, c = f & 7;
        uint4v val = *(const uint4v*)(base + t * 128 + ((c * 16) ^ ((t & 7) << 4)));
        *(uint4v*)(outn + f * 16) = val;
    }
}

// Main conv+GLU. 512 threads = 8 independent waves, NO LDS, NO barriers.
// Wave w: h2 = w&3 -> co in [16h2,16h2+16) (value) U [64+16h2,...) (gate);
// nh = w>>2 -> t in [32nh, 32nh+32). Grid-stride over samples; A-fragments
// and bias live in registers for the whole block.
// B-fragments: direct coalesced dwordx4 loads from xt[n][t][ci] with
// compile-time immediate offsets (zero per-load VALU).
__global__ __launch_bounds__(512, 4)
void conv_glu_xt(const ushort* __restrict__ xt, const ushort* __restrict__ wa,
                 const float* __restrict__ bias, float* __restrict__ out) {
    const int tid = threadIdx.x;
    const int w   = tid >> 6;      // wave id 0..7
    const int L   = tid & 63;
    const int l   = L & 15;
    const int q   = L >> 4;
    const int h2  = w & 3;         // co quarter
    const int nh  = w >> 2;        // t half
    const int t0  = nh * 32;

    // A fragments: 2 M-tiles (value, gate) x 6 K-chunks. 48 VGPR.
    // A[m=lane&15][k=q*8+j]; row co, kk = kc*32 + q*8 + j.
    short8 afr[2][6];
#pragma unroll
    for (int mt = 0; mt < 2; ++mt) {
        int co = 64 * mt + 16 * h2 + l;
        const short8* wrow = (const short8*)(wa + co * 192);
#pragma unroll
        for (int kc = 0; kc < 6; ++kc)
            afr[mt][kc] = wrow[kc * 4 + q];
    }

    float bv[4], bg[4];
#pragma unroll
    for (int r = 0; r < 4; ++r) {
        bv[r] = bias[16 * h2 + 4 * q + r];
        bg[r] = bias[64 + 16 * h2 + 4 * q + r];
    }

    const int stride = gridDim.x;
    for (int n = blockIdx.x; n < NSAMP; n += stride) {
        // lane base into xt sample: row t0+l, col-bytes q*16
        const char* bbase = (const char*)(xt + (long)n * (TLEN * CIN))
                            + (t0 + l) * 128 + q * 16;

        // acc initialized to bias (folds the epilogue bias add into MFMA C-in)
        float4v acc[2][2];
#pragma unroll
        for (int nt = 0; nt < 2; ++nt) {
            acc[0][nt] = (float4v){bv[0], bv[1], bv[2], bv[3]};
            acc[1][nt] = (float4v){bg[0], bg[1], bg[2], bg[3]};
        }

        // K loop: kc covers conv-tap kc>>1, ci half kc&1.
        // B[k=q*8+j][nn=l] = xt[t0 + nt*16 + l + tap][(kc&1)*32 + q*8 + j]
#pragma unroll
        for (int kc = 0; kc < 6; ++kc) {
            const int tap = kc >> 1;
            const int cib = (kc & 1) * 64;          // byte offset of ci half
#pragma unroll
            for (int nt = 0; nt < 2; ++nt) {
                // t up to 65 on the last rows: reads spill into the next
                // sample's rows (or the allocated slack after sample 9999);
                // those MFMA columns map to t>=62 outputs, which are discarded.
                const short8 bfr = *(const short8*)(bbase + (nt * 16 + tap) * 128 + cib);
                acc[0][nt] = __builtin_amdgcn_mfma_f32_16x16x32_bf16(
                    afr[0][kc], bfr, acc[0][nt], 0, 0, 0);
                acc[1][nt] = __builtin_amdgcn_mfma_f32_16x16x32_bf16(
                    afr[1][kc], bfr, acc[1][nt], 0, 0, 0);
            }
        }

        // Epilogue: GLU. D layout: row m = 4q+r -> co = 16h2+4q+r, col = l -> t.
        char* obase = (char*)out + (long)n * (COUT * TOUT * 4)
                      + (16 * h2 + 4 * q) * (TOUT * 4) + (t0 + l) * 4;
#pragma unroll
        for (int nt = 0; nt < 2; ++nt) {
            int t = t0 + nt * 16 + l;
            if (t < TOUT) {
#pragma unroll
                for (int r = 0; r < 4; ++r) {
                    float g  = acc[1][nt][r];
                    float sg = 1.0f / (1.0f + __expf(-g));
                    *(float*)(obase + r * (TOUT * 4) + nt * 64) = acc[0][nt][r] * sg;
                }
            }
        }
    }
}

// ---------------- Fallback (proven R1 kernel) if workspace is too small ----
__global__ __launch_bounds__(256, 4)
void conv_glu(const float* __restrict__ x, const ushort* __restrict__ wa,
              const float* __restrict__ bias, float* __restrict__ out) {
    __shared__ __align__(16) ushort xT[64 * 64];

    const int n   = blockIdx.x;
    const int tid = threadIdx.x;
    const int w   = tid >> 6;
    const int L   = tid & 63;
    const int l   = L & 15;
    const int q   = L >> 4;
    const int h   = w & 1;
    const int nh  = w >> 1;
    const int t0base = nh * 32;

    const float* xs = x + n * (CIN * TLEN);
    {
        const int cig = tid >> 4;
        const int ts  = (tid & 15) * 4;
        const float* p = xs + cig * 4 * TLEN + ts;
        float4v v0 = *(const float4v*)(p);
        float4v v1 = *(const float4v*)(p + TLEN);
        float4v v2 = *(const float4v*)(p + 2 * TLEN);
        float4v v3 = *(const float4v*)(p + 3 * TLEN);
        char* base = (char*)xT;
#pragma unroll
        for (int r = 0; r < 4; ++r) {
            int t = ts + r;
            uint2v val;
            val.x = cvt_pk_bf16(v0[r], v1[r]);
            val.y = cvt_pk_bf16(v2[r], v3[r]);
            *(uint2v*)(base + t * 128 + ((cig * 8) ^ ((t & 7) << 4))) = val;
        }
    }
    __syncthreads();

    const ushort* arow[4];
#pragma unroll
    for (int mt = 0; mt < 4; ++mt) {
        int co = 32 * h + 16 * (mt & 1) + 64 * (mt >> 1) + l;
        arow[mt] = wa + co * 192 + q * 8;
    }

    float4v acc[4][2];
#pragma unroll
    for (int mt = 0; mt < 4; ++mt)
#pragma unroll
        for (int nt = 0; nt < 2; ++nt)
            acc[mt][nt] = (float4v){0.f, 0.f, 0.f, 0.f};

#pragma unroll
    for (int kc = 0; kc < 6; ++kc) {
        short8 afr[4];
#pragma unroll
        for (int mt = 0; mt < 4; ++mt)
            afr[mt] = *(const short8*)(arow[mt] + kc * 32);

        const int tap  = kc >> 1;
        const int cib2 = (kc & 1) * 64 + q * 16;
#pragma unroll
        for (int nt = 0; nt < 2; ++nt) {
            int t = t0base + nt * 16 + l + tap;
            if (t > 63) t = 63;
            const short8 bfr = *(const short8*)((const char*)xT + t * 128
                                                + (cib2 ^ ((t & 7) << 4)));
#pragma unroll
            for (int mt = 0; mt < 4; ++mt)
                acc[mt][nt] = __builtin_amdgcn_mfma_f32_16x16x32_bf16(
                    afr[mt], bfr, acc[mt][nt], 0, 0, 0);
        }
    }

#pragma unroll
    for (int p2 = 0; p2 < 2; ++p2)
#pragma unroll
        for (int nt = 0; nt < 2; ++nt)
#pragma unroll
            for (int r = 0; r < 4; ++r) {
                int co = 32 * h + 16 * p2 + 4 * q + r;
                int t  = t0base + nt * 16 + l;
                float a = acc[p2][nt][r]     + bias[co];
                float g = acc[p2 + 2][nt][r] + bias[co + 64];
                float sg = 1.0f / (1.0f + __expf(-g));
                if (t < TOUT)
                    out[(n * COUT + co) * TOUT + t] = a * sg;
            }
}

extern "C" void kernel_launch(void* const* d_in, const int* in_sizes, int n_in,
                              void* d_out, int out_size, void* d_ws, size_t ws_size,
                              hipStream_t stream) {
    const float* x    = (const float*)d_in[0];
    const float* wt   = (const float*)d_in[1];
    const float* bias = (const float*)d_in[2];
    ushort*      wa   = (ushort*)d_ws;                       // 48 KB weights
    float*       out  = (float*)d_out;

    prep_weights<<<96, 256, 0, stream>>>(wt, wa);

    // xt needs 64 KB (wa, padded) + 10000*8KB + 4KB slack
    const size_t need = 65536 + (size_t)NSAMP * TLEN * CIN * 2 + 4096;
    if (ws_size >= need) {
        ushort* xxt = (ushort*)((char*)d_ws + 65536);
        prep_x<<<NSAMP, 256, 0, stream>>>(x, xxt);
        conv_glu_xt<<<2048, 512, 0, stream>>>(xxt, wa, bias, out);
    } else {
        conv_glu<<<NSAMP, 256, 0, stream>>>(x, wa, bias, out);
    }
}

// Round 4
// 327.661 us; speedup vs baseline: 1.2466x; 1.2466x over previous
//
#include <hip/hip_runtime.h>
#include <hip/hip_bf16.h>

typedef __attribute__((ext_vector_type(8))) short short8;
typedef __attribute__((ext_vector_type(4))) float float4v;
typedef __attribute__((ext_vector_type(2))) unsigned int uint2v;
typedef __attribute__((ext_vector_type(4))) unsigned int uint4v;

#define NSAMP 10000
#define CIN   64
#define TLEN  64
#define COUT  64     // channels after GLU
#define TOUT  62
#define SPX   2      // samples per prep_x block
#define SPW   8      // samples per conv block
#define CONVBLK (NSAMP / SPW)

// fp32 -> bf16 bits, round-to-nearest-even (inputs are never NaN/Inf)
static __device__ __forceinline__ ushort f2bf(float v) {
    unsigned int x = __float_as_uint(v);
    return (ushort)((x + 0x7fffu + ((x >> 16) & 1u)) >> 16);
}

// packed fp32x2 -> bf16x2 (lo = a, hi = b), RNE
static __device__ __forceinline__ unsigned int cvt_pk_bf16(float a, float b) {
    unsigned int r;
    asm("v_cvt_pk_bf16_f32 %0, %1, %2" : "=v"(r) : "v"(a), "v"(b));
    return r;
}

// async global->LDS, 16B per lane (dest = wave-uniform base + lane*16)
static __device__ __forceinline__ void stage16(const void* g, void* l) {
    typedef __attribute__((address_space(1))) const unsigned int guint;
    typedef __attribute__((address_space(3))) unsigned int luint;
    __builtin_amdgcn_global_load_lds((guint*)g, (luint*)l, 16, 0, 0);
}

// Pre-permute + downconvert weights: Wa[co][kk], kk = k*64 + ci (bf16 bits).
// src: float w[co][ci][k] (strides 192, 3, 1)
__global__ void prep_weights(const float* __restrict__ w, ushort* __restrict__ wa) {
    int o = blockIdx.x * blockDim.x + threadIdx.x;
    if (o >= 128 * 192) return;
    int co = o / 192;
    int kk = o - co * 192;
    int k  = kk >> 6;
    int ci = kk & 63;
    wa[o] = f2bf(w[co * 192 + ci * 3 + k]);
}

// prep_x v2: x[n][ci][t] fp32 -> xt[n] = SWIZZLED bf16 image:
//   image byte(2*ci ^ ((t&7)<<4)) of row t (128B rows).
// BARRIER-FREE: wave w owns t-rows [16w,16w+16) end-to-end (writes them,
// reads them back) -> in-wave lgkmcnt ordering only, waves free-run.
__global__ __launch_bounds__(256, 8)
void prep_x(const float* __restrict__ x, ushort* __restrict__ xt) {
    __shared__ __align__(16) ushort b[64 * 64];   // 8 KB, rows disjoint per wave
    const int tid = threadIdx.x;
    const int w   = tid >> 6;       // wave owns t in [16w, 16w+16)
    const int L   = tid & 63;
    const int a   = L & 31;         // ci pair (2a, 2a+1)
    const int g   = L >> 5;         // t subhalf of 8
    const int tb  = 16 * w + 8 * g;
    const long n0 = (long)blockIdx.x * SPX;
    char* lb = (char*)b;

    // preload both samples' slices (depth-covering: all loads issued upfront)
    const float* p0 = x + n0 * (CIN * TLEN) + (2 * a) * TLEN + tb;
    float4v A0 = *(const float4v*)(p0);
    float4v A1 = *(const float4v*)(p0 + 4);
    float4v A2 = *(const float4v*)(p0 + TLEN);
    float4v A3 = *(const float4v*)(p0 + TLEN + 4);
    const float* p1 = p0 + CIN * TLEN;
    float4v B0 = *(const float4v*)(p1);
    float4v B1 = *(const float4v*)(p1 + 4);
    float4v B2 = *(const float4v*)(p1 + TLEN);
    float4v B3 = *(const float4v*)(p1 + TLEN + 4);

#pragma unroll
    for (int s = 0; s < SPX; ++s) {
        float4v lo0 = s ? B0 : A0, lo1 = s ? B1 : A1;   // row 2a
        float4v hi0 = s ? B2 : A2, hi1 = s ? B3 : A3;   // row 2a+1
#pragma unroll
        for (int j = 0; j < 8; ++j) {
            int t = tb + j;
            float xa  = (j < 4) ? lo0[j & 3] : lo1[j & 3];
            float xb_ = (j < 4) ? hi0[j & 3] : hi1[j & 3];
            unsigned int val = cvt_pk_bf16(xa, xb_);
            *(unsigned int*)(lb + t * 128 + ((4 * a) ^ ((t & 7) << 4))) = val;
        }
        // writeback: wave copies ONLY its own rows, linearly (swizzle kept)
        char* dst = (char*)xt + (n0 + s) * (TLEN * CIN * 2);
        int o1 = w * 2048 + L * 16;
        uint4v d1 = *(const uint4v*)(lb + o1);
        uint4v d2 = *(const uint4v*)(lb + o1 + 1024);
        *(uint4v*)(dst + o1) = d1;
        *(uint4v*)(dst + o1 + 1024) = d2;
    }
}

// Main conv+GLU. 512 thr = 8 waves: h2 = w&3 -> co 16-row quarter (value +
// gate pair), nh = w>>2 -> t half. 8 samples/block, 3-deep LDS ring staged
// by global_load_lds, depth-2 prefetch, counted vmcnt (never 0 in loop),
// one raw s_barrier per sample. B-frags: swizzled ds_read_b128.
__global__ __launch_bounds__(512, 4)
void conv_glu_xt(const ushort* __restrict__ xt, const ushort* __restrict__ wa,
                 const float* __restrict__ bias, float* __restrict__ out) {
    // 66 rows/buffer: rows 0..63 staged, rows 64-65 = pad for tap overhang
    // (those B-columns map to out t>=62, discarded; garbage is safe).
    __shared__ __align__(16) ushort xb[3][66 * 64];   // 25.3 KB

    const int tid = threadIdx.x;
    const int w  = tid >> 6, L = tid & 63, l = L & 15, q = L >> 4;
    const int h2 = w & 3, nh = w >> 2, t0 = nh * 32;
    const long n0 = (long)blockIdx.x * SPW;

    // A fragments: 2 M-tiles (value, gate) x 6 K-chunks, registers all block.
    short8 afr[2][6];
#pragma unroll
    for (int mt = 0; mt < 2; ++mt) {
        int co = 64 * mt + 16 * h2 + l;
        const short8* wrow = (const short8*)(wa + co * 192);
#pragma unroll
        for (int kc = 0; kc < 6; ++kc)
            afr[mt][kc] = wrow[kc * 4 + q];
    }
    float bv[4], bg[4];
#pragma unroll
    for (int r = 0; r < 4; ++r) {
        bv[r] = bias[16 * h2 + 4 * q + r];
        bg[r] = bias[64 + 16 * h2 + 4 * q + r];
    }

    const char* gs = (const char*)xt + n0 * 8192 + tid * 16;
    // prologue: stage samples 0,1
    stage16(gs + 0 * 8192, &xb[0][tid * 8]);
    stage16(gs + 1 * 8192, &xb[1][tid * 8]);
    asm volatile("s_waitcnt vmcnt(1)" ::: "memory");   // sample 0 landed
    asm volatile("s_barrier" ::: "memory");

#pragma unroll
    for (int s = 0; s < SPW; ++s) {
        if (s + 2 < SPW)   // depth-2 prefetch into ring slot (s+2)%3
            stage16(gs + (long)(s + 2) * 8192, &xb[(s + 2) % 3][tid * 8]);

        const char* rb = (const char*)&xb[s % 3][0];
        float4v acc[2][2];
#pragma unroll
        for (int nt = 0; nt < 2; ++nt) {
            acc[0][nt] = (float4v){bv[0], bv[1], bv[2], bv[3]};
            acc[1][nt] = (float4v){bg[0], bg[1], bg[2], bg[3]};
        }

#pragma unroll
        for (int kc = 0; kc < 6; ++kc) {
            const int tap = kc >> 1;
            const int cib = (kc & 1) * 64 + q * 16;   // ci-slice byte offset
#pragma unroll
            for (int nt = 0; nt < 2; ++nt) {
                int t = t0 + nt * 16 + l + tap;       // row 0..65, in-bounds
                const short8 bfr = *(const short8*)(rb + t * 128
                                                    + (cib ^ ((t & 7) << 4)));
                acc[0][nt] = __builtin_amdgcn_mfma_f32_16x16x32_bf16(
                    afr[0][kc], bfr, acc[0][nt], 0, 0, 0);
                acc[1][nt] = __builtin_amdgcn_mfma_f32_16x16x32_bf16(
                    afr[1][kc], bfr, acc[1][nt], 0, 0, 0);
            }
        }

        // counted vmcnt: drain gload(s+1) only; keep gload(s+2) + stores in
        // flight. Ledger (1 gload/iter before this point, 8 stores/iter after
        // the previous barrier): s=0 -> 1; s=1..5 -> 8 stores + 1 gload = 9;
        // s=6 -> 8 (no gload(8)); s=7 -> none.
        if (s + 1 < SPW) {
            if (s == 0)      asm volatile("s_waitcnt vmcnt(1)" ::: "memory");
            else if (s < 6)  asm volatile("s_waitcnt vmcnt(9)" ::: "memory");
            else             asm volatile("s_waitcnt vmcnt(8)" ::: "memory");
            asm volatile("s_barrier" ::: "memory");
        }

        // epilogue: GLU, fp32 stores (after barrier: keeps vmcnt ledger small)
        char* ob = (char*)out + (n0 + s) * (COUT * TOUT * 4)
                   + (16 * h2 + 4 * q) * (TOUT * 4) + (t0 + l) * 4;
#pragma unroll
        for (int nt = 0; nt < 2; ++nt) {
            int t = t0 + nt * 16 + l;
            if (t < TOUT) {
#pragma unroll
                for (int r = 0; r < 4; ++r) {
                    float g2 = acc[1][nt][r];
                    float sg = 1.0f / (1.0f + __expf(-g2));
                    *(float*)(ob + r * (TOUT * 4) + nt * 64) = acc[0][nt][r] * sg;
                }
            }
        }
    }
}

// ---------------- Fallback (proven R1 kernel) if workspace is too small ----
__global__ __launch_bounds__(256, 4)
void conv_glu(const float* __restrict__ x, const ushort* __restrict__ wa,
              const float* __restrict__ bias, float* __restrict__ out) {
    __shared__ __align__(16) ushort xT[64 * 64];

    const int n   = blockIdx.x;
    const int tid = threadIdx.x;
    const int w   = tid >> 6;
    const int L   = tid & 63;
    const int l   = L & 15;
    const int q   = L >> 4;
    const int h   = w & 1;
    const int nh  = w >> 1;
    const int t0base = nh * 32;

    const float* xs = x + n * (CIN * TLEN);
    {
        const int cig = tid >> 4;
        const int ts  = (tid & 15) * 4;
        const float* p = xs + cig * 4 * TLEN + ts;
        float4v v0 = *(const float4v*)(p);
        float4v v1 = *(const float4v*)(p + TLEN);
        float4v v2 = *(const float4v*)(p + 2 * TLEN);
        float4v v3 = *(const float4v*)(p + 3 * TLEN);
        char* base = (char*)xT;
#pragma unroll
        for (int r = 0; r < 4; ++r) {
            int t = ts + r;
            uint2v val;
            val.x = cvt_pk_bf16(v0[r], v1[r]);
            val.y = cvt_pk_bf16(v2[r], v3[r]);
            *(uint2v*)(base + t * 128 + ((cig * 8) ^ ((t & 7) << 4))) = val;
        }
    }
    __syncthreads();

    const ushort* arow[4];
#pragma unroll
    for (int mt = 0; mt < 4; ++mt) {
        int co = 32 * h + 16 * (mt & 1) + 64 * (mt >> 1) + l;
        arow[mt] = wa + co * 192 + q * 8;
    }

    float4v acc[4][2];
#pragma unroll
    for (int mt = 0; mt < 4; ++mt)
#pragma unroll
        for (int nt = 0; nt < 2; ++nt)
            acc[mt][nt] = (float4v){0.f, 0.f, 0.f, 0.f};

#pragma unroll
    for (int kc = 0; kc < 6; ++kc) {
        short8 afr[4];
#pragma unroll
        for (int mt = 0; mt < 4; ++mt)
            afr[mt] = *(const short8*)(arow[mt] + kc * 32);

        const int tap  = kc >> 1;
        const int cib2 = (kc & 1) * 64 + q * 16;
#pragma unroll
        for (int nt = 0; nt < 2; ++nt) {
            int t = t0base + nt * 16 + l + tap;
            if (t > 63) t = 63;
            const short8 bfr = *(const short8*)((const char*)xT + t * 128
                                                + (cib2 ^ ((t & 7) << 4)));
#pragma unroll
            for (int mt = 0; mt < 4; ++mt)
                acc[mt][nt] = __builtin_amdgcn_mfma_f32_16x16x32_bf16(
                    afr[mt], bfr, acc[mt][nt], 0, 0, 0);
        }
    }

#pragma unroll
    for (int p2 = 0; p2 < 2; ++p2)
#pragma unroll
        for (int nt = 0; nt < 2; ++nt)
#pragma unroll
            for (int r = 0; r < 4; ++r) {
                int co = 32 * h + 16 * p2 + 4 * q + r;
                int t  = t0base + nt * 16 + l;
                float a = acc[p2][nt][r]     + bias[co];
                float g = acc[p2 + 2][nt][r] + bias[co + 64];
                float sg = 1.0f / (1.0f + __expf(-g));
                if (t < TOUT)
                    out[(n * COUT + co) * TOUT + t] = a * sg;
            }
}

extern "C" void kernel_launch(void* const* d_in, const int* in_sizes, int n_in,
                              void* d_out, int out_size, void* d_ws, size_t ws_size,
                              hipStream_t stream) {
    const float* x    = (const float*)d_in[0];
    const float* wt   = (const float*)d_in[1];
    const float* bias = (const float*)d_in[2];
    ushort*      wa   = (ushort*)d_ws;                       // 48 KB weights
    float*       out  = (float*)d_out;

    prep_weights<<<96, 256, 0, stream>>>(wt, wa);

    const size_t need = 65536 + (size_t)NSAMP * TLEN * CIN * 2 + 4096;
    if (ws_size >= need) {
        ushort* xxt = (ushort*)((char*)d_ws + 65536);
        prep_x<<<NSAMP / SPX, 256, 0, stream>>>(x, xxt);
        conv_glu_xt<<<CONVBLK, 512, 0, stream>>>(xxt, wa, bias, out);
    } else {
        conv_glu<<<NSAMP, 256, 0, stream>>>(x, wa, bias, out);
    }
}